// Round 8
// baseline (648.270 us; speedup 1.0000x reference)
//
#include <hip/hip_runtime.h>
#include <hip/hip_bf16.h>
#include <math.h>

constexpr int NN = 16384;   // nodes
constexpr int NE = 65536;   // edges
constexpr int NG = 512;     // graphs

typedef __attribute__((ext_vector_type(8)))  short short8;
typedef __attribute__((ext_vector_type(16))) float f32x16;

__device__ __forceinline__ short f2bf(float f) {          // f32 -> bf16 (RNE)
    unsigned u = __builtin_bit_cast(unsigned, f);
    return (short)((u + 0x7FFFu + ((u >> 16) & 1u)) >> 16);
}
__device__ __forceinline__ float b2f(unsigned short s) {  // bf16 -> f32
    return __builtin_bit_cast(float, (unsigned)s << 16);
}
__device__ __forceinline__ void gload_lds16(const unsigned short* g, unsigned short* l) {
    __builtin_amdgcn_global_load_lds(
        (const __attribute__((address_space(1))) unsigned int*)g,
        (__attribute__((address_space(3))) unsigned int*)l, 16, 0, 0);
}

// A-fragment: 8 bf16 = round(h[j] * e). Compiler fuses pairs to v_cvt_pk_bf16_f32.
__device__ __forceinline__ short8 agen(const float* h, float e) {
    unsigned u[4];
#pragma unroll
    for (int q = 0; q < 4; q++) {
        float2 p; p.x = h[2 * q] * e; p.y = h[2 * q + 1] * e;
        __hip_bfloat162 b = __float22bfloat162_rn(p);
        unsigned v; __builtin_memcpy(&v, &b, 4);
        u[q] = v;
    }
    uint4 uv = make_uint4(u[0], u[1], u[2], u[3]);
    return __builtin_bit_cast(short8, uv);
}

// ---------- node embedding: h = x @ ne_w + ne_b (f32 + bf16 outputs) ----------
__global__ void k_nh(const float* __restrict__ x, const float* __restrict__ w,
                     const float* __restrict__ b, float* __restrict__ h,
                     unsigned short* __restrict__ hbf) {
    int idx = blockIdx.x * 256 + threadIdx.x;     // n*64 + o
    int n = idx >> 6, o = idx & 63;
    const float* xr = x + n * 9;
    float s = b[o];
#pragma unroll
    for (int a = 0; a < 9; a++) s += xr[a] * w[a * 64 + o];
    h[idx] = s;
    hbf[idx] = (unsigned short)f2bf(s);
}

__global__ void k_deg(const int* __restrict__ ei, float* __restrict__ deg) {
    int e = blockIdx.x * 256 + threadIdx.x;
    atomicAdd(&deg[ei[NE + e]], 1.0f);
}

// ---------- fused edge MLP hidden, transposed bf16 output ----------
__global__ __launch_bounds__(256) void k_ewt(const float* __restrict__ ea,
                                             const float* __restrict__ eew,
                                             const float* __restrict__ eeb,
                                             const float* __restrict__ w1,
                                             const float* __restrict__ b1,
                                             unsigned short* __restrict__ ewT) {
    __shared__ float w1s[32 * 128];
    __shared__ float b1s[128];
    __shared__ float eews[96], eebs[32];
    int t = threadIdx.x;
    for (int c = t; c < 4096; c += 256) w1s[c] = w1[c];
    if (t < 128) b1s[t] = b1[t];
    if (t < 96)  eews[t] = eew[t];
    if (t < 32)  eebs[t] = eeb[t];
    __syncthreads();

    int e = blockIdx.x * 64 + (t & 63);
    int w = t >> 6;                                // wave -> ko quarter
    float a0 = ea[e * 3], a1 = ea[e * 3 + 1], a2 = ea[e * 3 + 2];
    float eer[32];
#pragma unroll
    for (int j = 0; j < 32; j++)
        eer[j] = eebs[j] + a0 * eews[j] + a1 * eews[32 + j] + a2 * eews[64 + j];
    float acc[32];
#pragma unroll
    for (int c = 0; c < 32; c++) acc[c] = b1s[w * 32 + c];
    for (int j = 0; j < 32; j++) {
        float ej = eer[j];
#pragma unroll
        for (int c = 0; c < 32; c++) acc[c] += ej * w1s[j * 128 + w * 32 + c];
    }
#pragma unroll
    for (int c = 0; c < 32; c++) {
        float v = fmaxf(acc[c], 0.f);
        ewT[(size_t)(w * 32 + c) * NE + e] = (unsigned short)f2bf(v);
    }
}

// ---------- pack w2 (+ b2 as slice kc=128, zeros kc=129..131) ----------
// w2p[kc][s][t][lane][j] = w2[kc, (s*16 + (lane>>5)*8 + j)*DOUT + t*32 + (lane&31)]
template <int DOUT>
__global__ void k_packw2(const float* __restrict__ w2, const float* __restrict__ b2,
                         unsigned short* __restrict__ w2p) {
    constexpr int TILES = DOUT / 32;
    int idx = blockIdx.x * 256 + threadIdx.x;
    int j = idx & 7, l = (idx >> 3) & 63;
    int rest = idx >> 9;
    int tt = rest % TILES;
    int s  = (rest / TILES) & 3;
    int kc = rest / (4 * TILES);
    int i = s * 16 + (l >> 5) * 8 + j;
    int o = tt * 32 + (l & 31);
    float v = (kc < 128) ? w2[(size_t)kc * 64 * DOUT + i * DOUT + o]
                         : (kc == 128 ? b2[i * DOUT + o] : 0.f);
    w2p[idx] = (unsigned short)f2bf(v);
}

// ---------- heavy kernel: 256 edges/block, 4 waves, M=64 per wave ----------
// K = 132 slices (128 ew + bias + 3 zero pads), CH=4 slices per LDS stage.
template <int DOUT>
__global__ __launch_bounds__(256, 1) void k_msg_mfma(const int* __restrict__ ei,
                                                     const unsigned short* __restrict__ hbf,
                                                     const unsigned short* __restrict__ ewT,
                                                     const unsigned short* __restrict__ w2p,
                                                     float* __restrict__ aggr) {
    constexpr int TILES = DOUT / 32;
    constexpr int SL    = 4 * TILES * 64 * 8;       // ushorts per k-slice (64:4096, 32:2048)
    constexpr int CH    = 4;
    constexpr int CHSL  = CH * SL;
    constexpr int NCHUNK = 33;                      // 132 slices
    __shared__ __align__(16) unsigned short w2s[2 * CHSL];

    int t = threadIdx.x;
    int w = t >> 6, l = t & 63;
    int hi = l >> 5, ln = l & 31;
    int eb = blockIdx.x * 256 + w * 64;             // wave's 64-edge base

    // hoist h[src] for both 32-edge tiles: i = s*16 + hi*8 + j
    float hf[2][4][8];
#pragma unroll
    for (int m = 0; m < 2; m++) {
        int sidx = ei[eb + m * 32 + ln];
        const unsigned short* hrow = hbf + (size_t)sidx * 64;
#pragma unroll
        for (int s = 0; s < 4; s++) {
            short8 hv = *(const short8*)(hrow + (s * 2 + hi) * 8);
#pragma unroll
            for (int j = 0; j < 8; j++) hf[m][s][j] = b2f((unsigned short)hv[j]);
        }
    }

    // stage chunk 0
    {
        const unsigned short* g = w2p;
        unsigned short* ld = w2s;
#pragma unroll
        for (int p = 0; p < CHSL / 2048; p++)
            gload_lds16(g + p * 2048 + t * 8, ld + p * 2048 + t * 8);
    }
    float ewn[2];
    ewn[0] = b2f(ewT[eb + ln]);
    ewn[1] = b2f(ewT[eb + 32 + ln]);

    f32x16 acc[2][TILES];
#pragma unroll
    for (int m = 0; m < 2; m++)
#pragma unroll
        for (int tt = 0; tt < TILES; tt++)
#pragma unroll
            for (int r = 0; r < 16; r++) acc[m][tt][r] = 0.f;

    __syncthreads();

    for (int c = 0; c < NCHUNK; c++) {
        if (c + 1 < NCHUNK) {                       // prefetch next chunk
            const unsigned short* g = w2p + (size_t)(c + 1) * CHSL;
            unsigned short* ld = w2s + ((c + 1) & 1) * CHSL;
#pragma unroll
            for (int p = 0; p < CHSL / 2048; p++)
                gload_lds16(g + p * 2048 + t * 8, ld + p * 2048 + t * 8);
        }
        const unsigned short* cbuf = w2s + (c & 1) * CHSL;
#pragma unroll
        for (int s2 = 0; s2 < CH; s2++) {
            int kc = c * CH + s2;
            float ewc0 = ewn[0], ewc1 = ewn[1];
            int kn = kc + 1;
            if (kn < 128) {
                ewn[0] = b2f(ewT[(size_t)kn * NE + eb + ln]);
                ewn[1] = b2f(ewT[(size_t)kn * NE + eb + 32 + ln]);
            } else {
                ewn[0] = ewn[1] = (kn == 128) ? 1.f : 0.f;
            }
            const unsigned short* sbuf = cbuf + s2 * SL;
#pragma unroll
            for (int s = 0; s < 4; s++) {
                short8 a0 = agen(hf[0][s], ewc0);
                short8 a1 = agen(hf[1][s], ewc1);
#pragma unroll
                for (int tt = 0; tt < TILES; tt++) {
                    short8 b = *(const short8*)(sbuf + ((s * TILES + tt) * 64 + l) * 8);
                    acc[0][tt] = __builtin_amdgcn_mfma_f32_32x32x16_bf16(a0, b, acc[0][tt], 0, 0, 0);
                    acc[1][tt] = __builtin_amdgcn_mfma_f32_32x32x16_bf16(a1, b, acc[1][tt], 0, 0, 0);
                }
            }
        }
        __syncthreads();
    }

    // epilogue: scatter-add. D: col = l&31, row = (r&3) + 8*(r>>2) + 4*hi
#pragma unroll
    for (int m = 0; m < 2; m++)
#pragma unroll
        for (int r = 0; r < 16; r++) {
            int row = (r & 3) + 8 * (r >> 2) + 4 * hi;
            int d = ei[NE + eb + m * 32 + row];
#pragma unroll
            for (int tt = 0; tt < TILES; tt++)
                atomicAdd(&aggr[(size_t)d * DOUT + tt * 32 + ln], acc[m][tt][r]);
        }
}

// ---------- combine: h @ root + aggr/deg + cb ----------
template <int DOUT>
__global__ void k_combine(const float* __restrict__ h, const float* __restrict__ root,
                          const float* __restrict__ aggr, const float* __restrict__ deg,
                          const float* __restrict__ cb, float* __restrict__ htmp) {
    int idx = blockIdx.x * 256 + threadIdx.x;
    int n = idx / DOUT, o = idx % DOUT;
    const float* hr = h + n * 64;
    float s = cb[o] + aggr[idx] / fmaxf(deg[n], 1.f);
#pragma unroll 8
    for (int i = 0; i < 64; i++) s += hr[i] * root[i * DOUT + o];
    htmp[idx] = s;
}

// ---------- BatchNorm: 8-way parallel partials + finalize ----------
template <int DOUT>
__global__ void k_bnstats(const float* __restrict__ htmp, float* __restrict__ sums) {
    int o = blockIdx.x >> 3, chunk = blockIdx.x & 7, t = threadIdx.x;
    float s = 0.f, q = 0.f;
    int n0 = chunk * (NN / 8);
    for (int n = n0 + t; n < n0 + NN / 8; n += 256) {
        float v = htmp[n * DOUT + o];
        s += v; q += v * v;
    }
    for (int off = 32; off; off >>= 1) { s += __shfl_down(s, off); q += __shfl_down(q, off); }
    __shared__ float ls[4], lq[4];
    int w = t >> 6;
    if ((t & 63) == 0) { ls[w] = s; lq[w] = q; }
    __syncthreads();
    if (t == 0) {
        s = ls[0] + ls[1] + ls[2] + ls[3];
        q = lq[0] + lq[1] + lq[2] + lq[3];
        atomicAdd(&sums[o], s);
        atomicAdd(&sums[DOUT + o], q);
    }
}

template <int DOUT>
__global__ void k_bnfinal(const float* __restrict__ sums, const float* __restrict__ g,
                          const float* __restrict__ bb, float* __restrict__ scale,
                          float* __restrict__ shift) {
    int o = threadIdx.x;
    if (o < DOUT) {
        float mean = sums[o] / NN;
        float var  = sums[DOUT + o] / NN - mean * mean;
        float sc   = g[o] * rsqrtf(var + 1e-5f);
        scale[o] = sc;
        shift[o] = bb[o] - mean * sc;
    }
}

template <int DOUT, bool WB>
__global__ void k_bnapply(const float* __restrict__ htmp, const float* __restrict__ scale,
                          const float* __restrict__ shift, float* __restrict__ hout,
                          unsigned short* __restrict__ hbf) {
    int idx = blockIdx.x * 256 + threadIdx.x;
    int o = idx & (DOUT - 1);
    float v = fmaxf(htmp[idx] * scale[o] + shift[o], 0.f);
    hout[idx] = v;
    if (WB) hbf[idx] = (unsigned short)f2bf(v);
}

// ---------- pool + fc ----------
__global__ void k_pool(const float* __restrict__ h, const int* __restrict__ batch,
                       float* __restrict__ pool, float* __restrict__ cnt) {
    int idx = blockIdx.x * 256 + threadIdx.x;   // n*32 + o
    int n = idx >> 5, o = idx & 31;
    int b = batch[n];
    atomicAdd(&pool[b * 32 + o], h[idx]);
    if (o == 0) atomicAdd(&cnt[b], 1.0f);
}

__global__ void k_fc(const float* __restrict__ pool, const float* __restrict__ cnt,
                     const float* __restrict__ w, const float* __restrict__ b,
                     float* __restrict__ out) {
    int idx = blockIdx.x * 256 + threadIdx.x;   // g*12 + t
    int gI = idx / 12, t = idx % 12;
    float inv = 1.f / fmaxf(cnt[gI], 1.f);
    float s = 0.f;
#pragma unroll 8
    for (int j = 0; j < 32; j++) s += pool[gI * 32 + j] * w[j * 12 + t];
    s = s * inv + b[t];
    out[idx] = 1.f / (1.f + expf(-s));
}

// ---------- launch ----------
extern "C" void kernel_launch(void* const* d_in, const int* in_sizes, int n_in,
                              void* d_out, int out_size, void* d_ws, size_t ws_size,
                              hipStream_t stream) {
    const float* x   = (const float*)d_in[0];
    const int*   ei  = (const int*)d_in[1];
    const float* ea  = (const float*)d_in[2];
    const int*   bat = (const int*)d_in[3];
    const float* eew = (const float*)d_in[4];
    const float* eeb = (const float*)d_in[5];
    const float* nw  = (const float*)d_in[6];
    const float* nb  = (const float*)d_in[7];
    const float* fcw = (const float*)d_in[32];
    const float* fcb = (const float*)d_in[33];
    float* out = (float*)d_out;

    char* ws = (char*)d_ws;
    unsigned short* ewT = (unsigned short*)(ws + 0);          // 128*E*2 = 16.78 MB
    unsigned short* w2p = (unsigned short*)(ws + 16777216);   // 132*8KB = 1.06 MB (pad 2MB)
    float* hA    = (float*)(ws + 18874368);                   // N*64*4
    float* hB    = (float*)(ws + 23068672);
    float* htmp  = (float*)(ws + 27262976);
    float* aggr  = (float*)(ws + 31457280);                   // N*64*4, ends 35651584
    float* sums  = (float*)(ws + 35651584);                   // 256 f (contiguous w/ aggr)
    unsigned short* hbf = (unsigned short*)(ws + 35652608);   // N*64*2
    float* deg   = (float*)(ws + 37749760);                   // N*4
    float* scale = (float*)(ws + 37815296);
    float* shift = (float*)(ws + 37815552);
    float* pool  = (float*)(ws + 37815808);                   // G*32*4
    float* cnt   = (float*)(ws + 37881344);                   // G*4

    (void)hipMemsetAsync(deg, 0, NN * 4, stream);
    (void)hipMemsetAsync(pool, 0, NG * 32 * 4 + NG * 4, stream);

    k_nh<<<NN * 64 / 256, 256, 0, stream>>>(x, nw, nb, hA, hbf);
    k_deg<<<NE / 256, 256, 0, stream>>>(ei, deg);

    float* hin = hA;
    float* hout = hB;
    for (int L = 0; L < 3; L++) {
        const float* w1 = (const float*)d_in[8 + 8 * L + 0];
        const float* b1 = (const float*)d_in[8 + 8 * L + 1];
        const float* w2 = (const float*)d_in[8 + 8 * L + 2];
        const float* b2 = (const float*)d_in[8 + 8 * L + 3];
        const float* rt = (const float*)d_in[8 + 8 * L + 4];
        const float* cb = (const float*)d_in[8 + 8 * L + 5];
        const float* bg = (const float*)d_in[8 + 8 * L + 6];
        const float* bb = (const float*)d_in[8 + 8 * L + 7];

        (void)hipMemsetAsync(aggr, 0, NN * 64 * 4 + 1024, stream);  // aggr + sums

        k_ewt<<<NE / 64, 256, 0, stream>>>(ea, eew, eeb, w1, b1, ewT);

        if (L < 2) {
            k_packw2<64><<<132 * 4096 / 256, 256, 0, stream>>>(w2, b2, w2p);
            k_msg_mfma<64><<<NE / 256, 256, 0, stream>>>(ei, hbf, ewT, w2p, aggr);
            k_combine<64><<<NN * 64 / 256, 256, 0, stream>>>(hin, rt, aggr, deg, cb, htmp);
            k_bnstats<64><<<64 * 8, 256, 0, stream>>>(htmp, sums);
            k_bnfinal<64><<<1, 64, 0, stream>>>(sums, bg, bb, scale, shift);
            k_bnapply<64, true><<<NN * 64 / 256, 256, 0, stream>>>(htmp, scale, shift, hout, hbf);
        } else {
            k_packw2<32><<<132 * 2048 / 256, 256, 0, stream>>>(w2, b2, w2p);
            k_msg_mfma<32><<<NE / 256, 256, 0, stream>>>(ei, hbf, ewT, w2p, aggr);
            k_combine<32><<<NN * 32 / 256, 256, 0, stream>>>(hin, rt, aggr, deg, cb, htmp);
            k_bnstats<32><<<32 * 8, 256, 0, stream>>>(htmp, sums);
            k_bnfinal<32><<<1, 64, 0, stream>>>(sums, bg, bb, scale, shift);
            k_bnapply<32, false><<<NN * 32 / 256, 256, 0, stream>>>(htmp, scale, shift, hout, hbf);
        }
        float* tmp = hin; hin = hout; hout = tmp;
    }
    k_pool<<<NN * 32 / 256, 256, 0, stream>>>(hin, bat, pool, cnt);
    k_fc<<<NG * 12 / 256, 256, 0, stream>>>(pool, cnt, fcw, fcb, out);
}

// Round 10
// 627.802 us; speedup vs baseline: 1.0326x; 1.0326x over previous
//
#include <hip/hip_runtime.h>
#include <hip/hip_bf16.h>
#include <math.h>

constexpr int NN = 16384;   // nodes
constexpr int NE = 65536;   // edges
constexpr int NG = 512;     // graphs

typedef __attribute__((ext_vector_type(8)))  short short8;
typedef __attribute__((ext_vector_type(16))) float f32x16;

__device__ __forceinline__ short f2bf(float f) {          // f32 -> bf16 (RNE)
    unsigned u = __builtin_bit_cast(unsigned, f);
    return (short)((u + 0x7FFFu + ((u >> 16) & 1u)) >> 16);
}
__device__ __forceinline__ float b2f(unsigned short s) {  // bf16 -> f32
    return __builtin_bit_cast(float, (unsigned)s << 16);
}
__device__ __forceinline__ void gload_lds16(const unsigned short* g, unsigned short* l) {
    __builtin_amdgcn_global_load_lds(
        (const __attribute__((address_space(1))) unsigned int*)g,
        (__attribute__((address_space(3))) unsigned int*)l, 16, 0, 0);
}

// A-fragment: 8 bf16 = round(h[j] * e). Compiler fuses pairs to v_cvt_pk_bf16_f32.
__device__ __forceinline__ short8 agen(const float* h, float e) {
    unsigned u[4];
#pragma unroll
    for (int q = 0; q < 4; q++) {
        float2 p; p.x = h[2 * q] * e; p.y = h[2 * q + 1] * e;
        __hip_bfloat162 b = __float22bfloat162_rn(p);
        unsigned v; __builtin_memcpy(&v, &b, 4);
        u[q] = v;
    }
    uint4 uv = make_uint4(u[0], u[1], u[2], u[3]);
    return __builtin_bit_cast(short8, uv);
}

// ---------- node embedding: h = x @ ne_w + ne_b (f32 + bf16 outputs) ----------
__global__ void k_nh(const float* __restrict__ x, const float* __restrict__ w,
                     const float* __restrict__ b, float* __restrict__ h,
                     unsigned short* __restrict__ hbf) {
    int idx = blockIdx.x * 256 + threadIdx.x;     // n*64 + o
    int n = idx >> 6, o = idx & 63;
    const float* xr = x + n * 9;
    float s = b[o];
#pragma unroll
    for (int a = 0; a < 9; a++) s += xr[a] * w[a * 64 + o];
    h[idx] = s;
    hbf[idx] = (unsigned short)f2bf(s);
}

__global__ void k_deg(const int* __restrict__ ei, float* __restrict__ deg) {
    int e = blockIdx.x * 256 + threadIdx.x;
    atomicAdd(&deg[ei[NE + e]], 1.0f);
}

// ---------- fused edge MLP hidden, transposed bf16 output ----------
__global__ __launch_bounds__(256) void k_ewt(const float* __restrict__ ea,
                                             const float* __restrict__ eew,
                                             const float* __restrict__ eeb,
                                             const float* __restrict__ w1,
                                             const float* __restrict__ b1,
                                             unsigned short* __restrict__ ewT) {
    __shared__ float w1s[32 * 128];
    __shared__ float b1s[128];
    __shared__ float eews[96], eebs[32];
    int t = threadIdx.x;
    for (int c = t; c < 4096; c += 256) w1s[c] = w1[c];
    if (t < 128) b1s[t] = b1[t];
    if (t < 96)  eews[t] = eew[t];
    if (t < 32)  eebs[t] = eeb[t];
    __syncthreads();

    int e = blockIdx.x * 64 + (t & 63);
    int w = t >> 6;                                // wave -> ko quarter
    float a0 = ea[e * 3], a1 = ea[e * 3 + 1], a2 = ea[e * 3 + 2];
    float eer[32];
#pragma unroll
    for (int j = 0; j < 32; j++)
        eer[j] = eebs[j] + a0 * eews[j] + a1 * eews[32 + j] + a2 * eews[64 + j];
    float acc[32];
#pragma unroll
    for (int c = 0; c < 32; c++) acc[c] = b1s[w * 32 + c];
    for (int j = 0; j < 32; j++) {
        float ej = eer[j];
#pragma unroll
        for (int c = 0; c < 32; c++) acc[c] += ej * w1s[j * 128 + w * 32 + c];
    }
#pragma unroll
    for (int c = 0; c < 32; c++) {
        float v = fmaxf(acc[c], 0.f);
        ewT[(size_t)(w * 32 + c) * NE + e] = (unsigned short)f2bf(v);
    }
}

// ---------- pack w2 (+ b2 as slice kc=128, zeros kc=129..131) ----------
// w2p[kc][s][t][lane][j] = w2[kc, (s*16 + (lane>>5)*8 + j)*DOUT + t*32 + (lane&31)]
template <int DOUT>
__global__ void k_packw2(const float* __restrict__ w2, const float* __restrict__ b2,
                         unsigned short* __restrict__ w2p) {
    constexpr int TILES = DOUT / 32;
    int idx = blockIdx.x * 256 + threadIdx.x;
    int j = idx & 7, l = (idx >> 3) & 63;
    int rest = idx >> 9;
    int tt = rest % TILES;
    int s  = (rest / TILES) & 3;
    int kc = rest / (4 * TILES);
    int i = s * 16 + (l >> 5) * 8 + j;
    int o = tt * 32 + (l & 31);
    float v = (kc < 128) ? w2[(size_t)kc * 64 * DOUT + i * DOUT + o]
                         : (kc == 128 ? b2[i * DOUT + o] : 0.f);
    w2p[idx] = (unsigned short)f2bf(v);
}

// ---------- heavy kernel v3: 128 edges/block, 2 waves, M=64/wave ----------
// grid 512 (2 blocks/CU). ew panel fully pre-staged in LDS (no global loads
// in chunk loop -> no vmcnt poisoning). CH=2 double-buffered w2 staging.
template <int DOUT>
__global__ __launch_bounds__(128, 1) void k_msg_mfma(const int* __restrict__ ei,
                                                     const unsigned short* __restrict__ hbf,
                                                     const unsigned short* __restrict__ ewT,
                                                     const unsigned short* __restrict__ w2p,
                                                     float* __restrict__ aggr) {
    constexpr int TILES = DOUT / 32;
    constexpr int SL    = 4 * TILES * 64 * 8;       // ushorts per k-slice (64:4096, 32:2048)
    constexpr int CH    = 2;
    constexpr int CHSL  = CH * SL;
    constexpr int NCH   = 66;                       // 132 slices
    __shared__ __align__(16) unsigned short w2s[2 * CHSL];     // 64:32KB, 32:16KB
    __shared__ __align__(16) unsigned short ews[136 * 128];    // 34KB ew panel

    int t = threadIdx.x;                 // 0..127
    int w = t >> 6, l = t & 63;
    int hi = l >> 5, ln = l & 31;
    int eb = blockIdx.x * 128;           // block's 128-edge base
    int ew0 = w * 64;                    // wave's edge offset in block

    // ---- stage ew panel: 136 rows x 128 edges (rows >=128 clamped; overridden below)
#pragma unroll
    for (int i = 0; i < 17; i++) {
        int row = i * 8 + (t >> 4);
        int rowc = row < 128 ? row : 127;
        gload_lds16(ewT + (size_t)rowc * NE + eb + (t & 15) * 8,
                    ews + i * 1024 + t * 8);
    }
    // ---- stage w2 chunk 0
#pragma unroll
    for (int p = 0; p < CHSL / 1024; p++)
        gload_lds16(w2p + p * 1024 + t * 8, w2s + p * 1024 + t * 8);

    // hoist h[src] for both 32-edge tiles: i = s*16 + hi*8 + j
    float hf[2][4][8];
#pragma unroll
    for (int m = 0; m < 2; m++) {
        int sidx = ei[eb + ew0 + m * 32 + ln];
        const unsigned short* hrow = hbf + (size_t)sidx * 64;
#pragma unroll
        for (int s = 0; s < 4; s++) {
            short8 hv = *(const short8*)(hrow + (s * 2 + hi) * 8);
#pragma unroll
            for (int j = 0; j < 8; j++) hf[m][s][j] = b2f((unsigned short)hv[j]);
        }
    }

    f32x16 acc[2][TILES];
#pragma unroll
    for (int m = 0; m < 2; m++)
#pragma unroll
        for (int tt = 0; tt < TILES; tt++)
#pragma unroll
            for (int r = 0; r < 16; r++) acc[m][tt][r] = 0.f;

    __syncthreads();

    for (int c = 0; c < NCH; c++) {
        if (c + 1 < NCH) {                          // prefetch next w2 chunk
            const unsigned short* g = w2p + (size_t)(c + 1) * CHSL;
            unsigned short* ld = w2s + ((c + 1) & 1) * CHSL;
#pragma unroll
            for (int p = 0; p < CHSL / 1024; p++)
                gload_lds16(g + p * 1024 + t * 8, ld + p * 1024 + t * 8);
        }
        const unsigned short* cbuf = w2s + (c & 1) * CHSL;
#pragma unroll
        for (int s2 = 0; s2 < CH; s2++) {
            int kc = c * CH + s2;
            float r0 = b2f(ews[kc * 128 + ew0 + ln]);
            float r1 = b2f(ews[kc * 128 + ew0 + 32 + ln]);
            float ewc0 = (kc < 128) ? r0 : (kc == 128 ? 1.f : 0.f);
            float ewc1 = (kc < 128) ? r1 : (kc == 128 ? 1.f : 0.f);
            const unsigned short* sbuf = cbuf + s2 * SL;
#pragma unroll
            for (int s = 0; s < 4; s++) {
                short8 a0 = agen(hf[0][s], ewc0);
                short8 a1 = agen(hf[1][s], ewc1);
#pragma unroll
                for (int tt = 0; tt < TILES; tt++) {
                    short8 b = *(const short8*)(sbuf + ((s * TILES + tt) * 64 + l) * 8);
                    acc[0][tt] = __builtin_amdgcn_mfma_f32_32x32x16_bf16(a0, b, acc[0][tt], 0, 0, 0);
                    acc[1][tt] = __builtin_amdgcn_mfma_f32_32x32x16_bf16(a1, b, acc[1][tt], 0, 0, 0);
                }
            }
        }
        __syncthreads();
    }

    // epilogue: scatter-add. D: col = l&31, row = (r&3) + 8*(r>>2) + 4*hi
#pragma unroll
    for (int m = 0; m < 2; m++)
#pragma unroll
        for (int r = 0; r < 16; r++) {
            int row = (r & 3) + 8 * (r >> 2) + 4 * hi;
            int d = ei[NE + eb + ew0 + m * 32 + row];
#pragma unroll
            for (int tt = 0; tt < TILES; tt++)
                atomicAdd(&aggr[(size_t)d * DOUT + tt * 32 + ln], acc[m][tt][r]);
        }
}

// ---------- combine: h @ root + aggr/deg + cb ----------
template <int DOUT>
__global__ void k_combine(const float* __restrict__ h, const float* __restrict__ root,
                          const float* __restrict__ aggr, const float* __restrict__ deg,
                          const float* __restrict__ cb, float* __restrict__ htmp) {
    int idx = blockIdx.x * 256 + threadIdx.x;
    int n = idx / DOUT, o = idx % DOUT;
    const float* hr = h + n * 64;
    float s = cb[o] + aggr[idx] / fmaxf(deg[n], 1.f);
#pragma unroll 8
    for (int i = 0; i < 64; i++) s += hr[i] * root[i * DOUT + o];
    htmp[idx] = s;
}

// ---------- BatchNorm: 8-way parallel partials + finalize ----------
template <int DOUT>
__global__ void k_bnstats(const float* __restrict__ htmp, float* __restrict__ sums) {
    int o = blockIdx.x >> 3, chunk = blockIdx.x & 7, t = threadIdx.x;
    float s = 0.f, q = 0.f;
    int n0 = chunk * (NN / 8);
    for (int n = n0 + t; n < n0 + NN / 8; n += 256) {
        float v = htmp[n * DOUT + o];
        s += v; q += v * v;
    }
    for (int off = 32; off; off >>= 1) { s += __shfl_down(s, off); q += __shfl_down(q, off); }
    __shared__ float ls[4], lq[4];
    int w = t >> 6;
    if ((t & 63) == 0) { ls[w] = s; lq[w] = q; }
    __syncthreads();
    if (t == 0) {
        s = ls[0] + ls[1] + ls[2] + ls[3];
        q = lq[0] + lq[1] + lq[2] + lq[3];
        atomicAdd(&sums[o], s);
        atomicAdd(&sums[DOUT + o], q);
    }
}

template <int DOUT>
__global__ void k_bnfinal(const float* __restrict__ sums, const float* __restrict__ g,
                          const float* __restrict__ bb, float* __restrict__ scale,
                          float* __restrict__ shift) {
    int o = threadIdx.x;
    if (o < DOUT) {
        float mean = sums[o] / NN;
        float var  = sums[DOUT + o] / NN - mean * mean;
        float sc   = g[o] * rsqrtf(var + 1e-5f);
        scale[o] = sc;
        shift[o] = bb[o] - mean * sc;
    }
}

template <int DOUT, bool WB>
__global__ void k_bnapply(const float* __restrict__ htmp, const float* __restrict__ scale,
                          const float* __restrict__ shift, float* __restrict__ hout,
                          unsigned short* __restrict__ hbf) {
    int idx = blockIdx.x * 256 + threadIdx.x;
    int o = idx & (DOUT - 1);
    float v = fmaxf(htmp[idx] * scale[o] + shift[o], 0.f);
    hout[idx] = v;
    if (WB) hbf[idx] = (unsigned short)f2bf(v);
}

// ---------- pool + fc ----------
__global__ void k_pool(const float* __restrict__ h, const int* __restrict__ batch,
                       float* __restrict__ pool, float* __restrict__ cnt) {
    int idx = blockIdx.x * 256 + threadIdx.x;   // n*32 + o
    int n = idx >> 5, o = idx & 31;
    int b = batch[n];
    atomicAdd(&pool[b * 32 + o], h[idx]);
    if (o == 0) atomicAdd(&cnt[b], 1.0f);
}

__global__ void k_fc(const float* __restrict__ pool, const float* __restrict__ cnt,
                     const float* __restrict__ w, const float* __restrict__ b,
                     float* __restrict__ out) {
    int idx = blockIdx.x * 256 + threadIdx.x;   // g*12 + t
    int gI = idx / 12, t = idx % 12;
    float inv = 1.f / fmaxf(cnt[gI], 1.f);
    float s = 0.f;
#pragma unroll 8
    for (int j = 0; j < 32; j++) s += pool[gI * 32 + j] * w[j * 12 + t];
    s = s * inv + b[t];
    out[idx] = 1.f / (1.f + expf(-s));
}

// ---------- launch ----------
extern "C" void kernel_launch(void* const* d_in, const int* in_sizes, int n_in,
                              void* d_out, int out_size, void* d_ws, size_t ws_size,
                              hipStream_t stream) {
    const float* x   = (const float*)d_in[0];
    const int*   ei  = (const int*)d_in[1];
    const float* ea  = (const float*)d_in[2];
    const int*   bat = (const int*)d_in[3];
    const float* eew = (const float*)d_in[4];
    const float* eeb = (const float*)d_in[5];
    const float* nw  = (const float*)d_in[6];
    const float* nb  = (const float*)d_in[7];
    const float* fcw = (const float*)d_in[32];
    const float* fcb = (const float*)d_in[33];
    float* out = (float*)d_out;

    char* ws = (char*)d_ws;
    unsigned short* ewT = (unsigned short*)(ws + 0);          // 128*E*2 = 16.78 MB
    unsigned short* w2p = (unsigned short*)(ws + 16777216);   // 132*8KB = 1.06 MB (pad 2MB)
    float* hA    = (float*)(ws + 18874368);                   // N*64*4
    float* hB    = (float*)(ws + 23068672);
    float* htmp  = (float*)(ws + 27262976);
    float* aggr  = (float*)(ws + 31457280);                   // N*64*4, ends 35651584
    float* sums  = (float*)(ws + 35651584);                   // 256 f (contiguous w/ aggr)
    unsigned short* hbf = (unsigned short*)(ws + 35652608);   // N*64*2
    float* deg   = (float*)(ws + 37749760);                   // N*4
    float* scale = (float*)(ws + 37815296);
    float* shift = (float*)(ws + 37815552);
    float* pool  = (float*)(ws + 37815808);                   // G*32*4
    float* cnt   = (float*)(ws + 37881344);                   // G*4

    (void)hipMemsetAsync(deg, 0, NN * 4, stream);
    (void)hipMemsetAsync(pool, 0, NG * 32 * 4 + NG * 4, stream);

    k_nh<<<NN * 64 / 256, 256, 0, stream>>>(x, nw, nb, hA, hbf);
    k_deg<<<NE / 256, 256, 0, stream>>>(ei, deg);

    float* hin = hA;
    float* hout = hB;
    for (int L = 0; L < 3; L++) {
        const float* w1 = (const float*)d_in[8 + 8 * L + 0];
        const float* b1 = (const float*)d_in[8 + 8 * L + 1];
        const float* w2 = (const float*)d_in[8 + 8 * L + 2];
        const float* b2 = (const float*)d_in[8 + 8 * L + 3];
        const float* rt = (const float*)d_in[8 + 8 * L + 4];
        const float* cb = (const float*)d_in[8 + 8 * L + 5];
        const float* bg = (const float*)d_in[8 + 8 * L + 6];
        const float* bb = (const float*)d_in[8 + 8 * L + 7];

        (void)hipMemsetAsync(aggr, 0, NN * 64 * 4 + 1024, stream);  // aggr + sums

        k_ewt<<<NE / 64, 256, 0, stream>>>(ea, eew, eeb, w1, b1, ewT);

        if (L < 2) {
            k_packw2<64><<<132 * 4096 / 256, 256, 0, stream>>>(w2, b2, w2p);
            k_msg_mfma<64><<<NE / 128, 128, 0, stream>>>(ei, hbf, ewT, w2p, aggr);
            k_combine<64><<<NN * 64 / 256, 256, 0, stream>>>(hin, rt, aggr, deg, cb, htmp);
            k_bnstats<64><<<64 * 8, 256, 0, stream>>>(htmp, sums);
            k_bnfinal<64><<<1, 64, 0, stream>>>(sums, bg, bb, scale, shift);
            k_bnapply<64, true><<<NN * 64 / 256, 256, 0, stream>>>(htmp, scale, shift, hout, hbf);
        } else {
            k_packw2<32><<<132 * 2048 / 256, 256, 0, stream>>>(w2, b2, w2p);
            k_msg_mfma<32><<<NE / 128, 128, 0, stream>>>(ei, hbf, ewT, w2p, aggr);
            k_combine<32><<<NN * 32 / 256, 256, 0, stream>>>(hin, rt, aggr, deg, cb, htmp);
            k_bnstats<32><<<32 * 8, 256, 0, stream>>>(htmp, sums);
            k_bnfinal<32><<<1, 64, 0, stream>>>(sums, bg, bb, scale, shift);
            k_bnapply<32, false><<<NN * 32 / 256, 256, 0, stream>>>(htmp, scale, shift, hout, hbf);
        }
        float* tmp = hin; hin = hout; hout = tmp;
    }
    k_pool<<<NN * 32 / 256, 256, 0, stream>>>(hin, bat, pool, cnt);
    k_fc<<<NG * 12 / 256, 256, 0, stream>>>(pool, cnt, fcw, fcb, out);
}

// Round 14
// 514.417 us; speedup vs baseline: 1.2602x; 1.2204x over previous
//
#include <hip/hip_runtime.h>
#include <hip/hip_bf16.h>
#include <math.h>

constexpr int NN = 16384;   // nodes
constexpr int NE = 65536;   // edges
constexpr int NG = 512;     // graphs

typedef __attribute__((ext_vector_type(8)))  short short8;
typedef __attribute__((ext_vector_type(16))) float f32x16;

__device__ __forceinline__ short f2bf(float f) {          // f32 -> bf16 (RNE)
    unsigned u = __builtin_bit_cast(unsigned, f);
    return (short)((u + 0x7FFFu + ((u >> 16) & 1u)) >> 16);
}
__device__ __forceinline__ float b2f(unsigned short s) {  // bf16 -> f32
    return __builtin_bit_cast(float, (unsigned)s << 16);
}
__device__ __forceinline__ void gload_lds16(const unsigned short* g, unsigned short* l) {
    __builtin_amdgcn_global_load_lds(
        (const __attribute__((address_space(1))) unsigned int*)g,
        (__attribute__((address_space(3))) unsigned int*)l, 16, 0, 0);
}

// A-fragment: 8 bf16 = round(h[j] * e). Compiler fuses pairs to v_cvt_pk_bf16_f32.
__device__ __forceinline__ short8 agen(const float* h, float e) {
    unsigned u[4];
#pragma unroll
    for (int q = 0; q < 4; q++) {
        float2 p; p.x = h[2 * q] * e; p.y = h[2 * q + 1] * e;
        __hip_bfloat162 b = __float22bfloat162_rn(p);
        unsigned v; __builtin_memcpy(&v, &b, 4);
        u[q] = v;
    }
    uint4 uv = make_uint4(u[0], u[1], u[2], u[3]);
    return __builtin_bit_cast(short8, uv);
}

// ---------- node embedding: h = x @ ne_w + ne_b (f32 + bf16 outputs) ----------
__global__ void k_nh(const float* __restrict__ x, const float* __restrict__ w,
                     const float* __restrict__ b, float* __restrict__ h,
                     unsigned short* __restrict__ hbf) {
    int idx = blockIdx.x * 256 + threadIdx.x;     // n*64 + o
    int n = idx >> 6, o = idx & 63;
    const float* xr = x + n * 9;
    float s = b[o];
#pragma unroll
    for (int a = 0; a < 9; a++) s += xr[a] * w[a * 64 + o];
    h[idx] = s;
    hbf[idx] = (unsigned short)f2bf(s);
}

__global__ void k_deg(const int* __restrict__ ei, float* __restrict__ deg) {
    int e = blockIdx.x * 256 + threadIdx.x;
    atomicAdd(&deg[ei[NE + e]], 1.0f);
}

// ---------- fused edge MLP hidden, transposed bf16 output ----------
__global__ __launch_bounds__(256) void k_ewt(const float* __restrict__ ea,
                                             const float* __restrict__ eew,
                                             const float* __restrict__ eeb,
                                             const float* __restrict__ w1,
                                             const float* __restrict__ b1,
                                             unsigned short* __restrict__ ewT) {
    __shared__ float w1s[32 * 128];
    __shared__ float b1s[128];
    __shared__ float eews[96], eebs[32];
    int t = threadIdx.x;
    for (int c = t; c < 4096; c += 256) w1s[c] = w1[c];
    if (t < 128) b1s[t] = b1[t];
    if (t < 96)  eews[t] = eew[t];
    if (t < 32)  eebs[t] = eeb[t];
    __syncthreads();

    int e = blockIdx.x * 64 + (t & 63);
    int w = t >> 6;                                // wave -> ko quarter
    float a0 = ea[e * 3], a1 = ea[e * 3 + 1], a2 = ea[e * 3 + 2];
    float eer[32];
#pragma unroll
    for (int j = 0; j < 32; j++)
        eer[j] = eebs[j] + a0 * eews[j] + a1 * eews[32 + j] + a2 * eews[64 + j];
    float acc[32];
#pragma unroll
    for (int c = 0; c < 32; c++) acc[c] = b1s[w * 32 + c];
    for (int j = 0; j < 32; j++) {
        float ej = eer[j];
#pragma unroll
        for (int c = 0; c < 32; c++) acc[c] += ej * w1s[j * 128 + w * 32 + c];
    }
#pragma unroll
    for (int c = 0; c < 32; c++) {
        float v = fmaxf(acc[c], 0.f);
        ewT[(size_t)(w * 32 + c) * NE + e] = (unsigned short)f2bf(v);
    }
}

// ---------- pack w2 (+ b2 as slice kc=128, zeros kc=129..131) ----------
// w2p[kc][s][t][lane][j] = w2[kc, (s*16 + (lane>>5)*8 + j)*DOUT + t*32 + (lane&31)]
template <int DOUT>
__global__ void k_packw2(const float* __restrict__ w2, const float* __restrict__ b2,
                         unsigned short* __restrict__ w2p) {
    constexpr int TILES = DOUT / 32;
    int idx = blockIdx.x * 256 + threadIdx.x;
    int j = idx & 7, l = (idx >> 3) & 63;
    int rest = idx >> 9;
    int tt = rest % TILES;
    int s  = (rest / TILES) & 3;
    int kc = rest / (4 * TILES);
    int i = s * 16 + (l >> 5) * 8 + j;
    int o = tt * 32 + (l & 31);
    float v = (kc < 128) ? w2[(size_t)kc * 64 * DOUT + i * DOUT + o]
                         : (kc == 128 ? b2[i * DOUT + o] : 0.f);
    w2p[idx] = (unsigned short)f2bf(v);
}

// ---------- heavy kernel v4: 128 edges/block, 4 waves, M=32/wave ----------
// grid 512 -> 2 blocks/CU -> 8 waves/CU -> 2 waves/SIMD (latency hiding!).
// ew panel fully pre-staged in LDS; CH=2 double-buffered w2 staging.
template <int DOUT>
__global__ __launch_bounds__(256, 2) void k_msg_mfma(const int* __restrict__ ei,
                                                     const unsigned short* __restrict__ hbf,
                                                     const unsigned short* __restrict__ ewT,
                                                     const unsigned short* __restrict__ w2p,
                                                     float* __restrict__ aggr) {
    constexpr int TILES = DOUT / 32;
    constexpr int SL    = 4 * TILES * 64 * 8;       // ushorts per k-slice (64:4096, 32:2048)
    constexpr int CH    = 2;
    constexpr int CHSL  = CH * SL;
    constexpr int NCH   = 66;                       // 132 slices
    __shared__ __align__(16) unsigned short w2s[2 * CHSL];     // 64:32KB, 32:16KB
    __shared__ __align__(16) unsigned short ews[144 * 128];    // 36.9KB panel (pad 144 rows)

    int t = threadIdx.x;                 // 0..255
    int w = t >> 6, l = t & 63;
    int hi = l >> 5, ln = l & 31;
    int eb = blockIdx.x * 128;           // block's 128-edge base
    int e0 = w * 32;                     // wave's 32-edge offset in block

    // ---- stage ew panel: 9 iters x 256 thr x 16B; dst linear, src row-clamped
#pragma unroll
    for (int i = 0; i < 9; i++) {
        int idx = i * 256 + t;
        int row = idx >> 4;
        int rowc = row < 128 ? row : 127;
        gload_lds16(ewT + (size_t)rowc * NE + eb + (idx & 15) * 8,
                    ews + idx * 8);
    }
    // ---- stage w2 chunk 0
#pragma unroll
    for (int p = 0; p < CHSL / 2048; p++)
        gload_lds16(w2p + p * 2048 + t * 8, w2s + p * 2048 + t * 8);

    // hoist h[src] for this wave's 32-edge tile: i = s*16 + hi*8 + j
    float hf[4][8];
    {
        int sidx = ei[eb + e0 + ln];
        const unsigned short* hrow = hbf + (size_t)sidx * 64;
#pragma unroll
        for (int s = 0; s < 4; s++) {
            short8 hv = *(const short8*)(hrow + (s * 2 + hi) * 8);
#pragma unroll
            for (int j = 0; j < 8; j++) hf[s][j] = b2f((unsigned short)hv[j]);
        }
    }

    f32x16 acc[TILES];
#pragma unroll
    for (int tt = 0; tt < TILES; tt++)
#pragma unroll
        for (int r = 0; r < 16; r++) acc[tt][r] = 0.f;

    __syncthreads();

    for (int c = 0; c < NCH; c++) {
        if (c + 1 < NCH) {                          // prefetch next w2 chunk
            const unsigned short* g = w2p + (size_t)(c + 1) * CHSL;
            unsigned short* ld = w2s + ((c + 1) & 1) * CHSL;
#pragma unroll
            for (int p = 0; p < CHSL / 2048; p++)
                gload_lds16(g + p * 2048 + t * 8, ld + p * 2048 + t * 8);
        }
        const unsigned short* cbuf = w2s + (c & 1) * CHSL;
#pragma unroll
        for (int s2 = 0; s2 < CH; s2++) {
            int kc = c * CH + s2;
            float rv = b2f(ews[kc * 128 + e0 + ln]);
            float ewc = (kc < 128) ? rv : (kc == 128 ? 1.f : 0.f);
            const unsigned short* sbuf = cbuf + s2 * SL;
#pragma unroll
            for (int s = 0; s < 4; s++) {
                short8 a = agen(hf[s], ewc);
#pragma unroll
                for (int tt = 0; tt < TILES; tt++) {
                    short8 b = *(const short8*)(sbuf + ((s * TILES + tt) * 64 + l) * 8);
                    acc[tt] = __builtin_amdgcn_mfma_f32_32x32x16_bf16(a, b, acc[tt], 0, 0, 0);
                }
            }
        }
        __syncthreads();
    }

    // epilogue: scatter-add. D: col = l&31, row = (r&3) + 8*(r>>2) + 4*hi
#pragma unroll
    for (int r = 0; r < 16; r++) {
        int row = (r & 3) + 8 * (r >> 2) + 4 * hi;
        int d = ei[NE + eb + e0 + row];
#pragma unroll
        for (int tt = 0; tt < TILES; tt++)
            atomicAdd(&aggr[(size_t)d * DOUT + tt * 32 + ln], acc[tt][r]);
    }
}

// ---------- combine: h @ root + aggr/deg + cb ----------
template <int DOUT>
__global__ void k_combine(const float* __restrict__ h, const float* __restrict__ root,
                          const float* __restrict__ aggr, const float* __restrict__ deg,
                          const float* __restrict__ cb, float* __restrict__ htmp) {
    int idx = blockIdx.x * 256 + threadIdx.x;
    int n = idx / DOUT, o = idx % DOUT;
    const float* hr = h + n * 64;
    float s = cb[o] + aggr[idx] / fmaxf(deg[n], 1.f);
#pragma unroll 8
    for (int i = 0; i < 64; i++) s += hr[i] * root[i * DOUT + o];
    htmp[idx] = s;
}

// ---------- BatchNorm: 8-way parallel partials + finalize ----------
template <int DOUT>
__global__ void k_bnstats(const float* __restrict__ htmp, float* __restrict__ sums) {
    int o = blockIdx.x >> 3, chunk = blockIdx.x & 7, t = threadIdx.x;
    float s = 0.f, q = 0.f;
    int n0 = chunk * (NN / 8);
    for (int n = n0 + t; n < n0 + NN / 8; n += 256) {
        float v = htmp[n * DOUT + o];
        s += v; q += v * v;
    }
    for (int off = 32; off; off >>= 1) { s += __shfl_down(s, off); q += __shfl_down(q, off); }
    __shared__ float ls[4], lq[4];
    int w = t >> 6;
    if ((t & 63) == 0) { ls[w] = s; lq[w] = q; }
    __syncthreads();
    if (t == 0) {
        s = ls[0] + ls[1] + ls[2] + ls[3];
        q = lq[0] + lq[1] + lq[2] + lq[3];
        atomicAdd(&sums[o], s);
        atomicAdd(&sums[DOUT + o], q);
    }
}

template <int DOUT>
__global__ void k_bnfinal(const float* __restrict__ sums, const float* __restrict__ g,
                          const float* __restrict__ bb, float* __restrict__ scale,
                          float* __restrict__ shift) {
    int o = threadIdx.x;
    if (o < DOUT) {
        float mean = sums[o] / NN;
        float var  = sums[DOUT + o] / NN - mean * mean;
        float sc   = g[o] * rsqrtf(var + 1e-5f);
        scale[o] = sc;
        shift[o] = bb[o] - mean * sc;
    }
}

template <int DOUT, bool WB>
__global__ void k_bnapply(const float* __restrict__ htmp, const float* __restrict__ scale,
                          const float* __restrict__ shift, float* __restrict__ hout,
                          unsigned short* __restrict__ hbf) {
    int idx = blockIdx.x * 256 + threadIdx.x;
    int o = idx & (DOUT - 1);
    float v = fmaxf(htmp[idx] * scale[o] + shift[o], 0.f);
    hout[idx] = v;
    if (WB) hbf[idx] = (unsigned short)f2bf(v);
}

// ---------- pool + fc ----------
__global__ void k_pool(const float* __restrict__ h, const int* __restrict__ batch,
                       float* __restrict__ pool, float* __restrict__ cnt) {
    int idx = blockIdx.x * 256 + threadIdx.x;   // n*32 + o
    int n = idx >> 5, o = idx & 31;
    int b = batch[n];
    atomicAdd(&pool[b * 32 + o], h[idx]);
    if (o == 0) atomicAdd(&cnt[b], 1.0f);
}

__global__ void k_fc(const float* __restrict__ pool, const float* __restrict__ cnt,
                     const float* __restrict__ w, const float* __restrict__ b,
                     float* __restrict__ out) {
    int idx = blockIdx.x * 256 + threadIdx.x;   // g*12 + t
    int gI = idx / 12, t = idx % 12;
    float inv = 1.f / fmaxf(cnt[gI], 1.f);
    float s = 0.f;
#pragma unroll 8
    for (int j = 0; j < 32; j++) s += pool[gI * 32 + j] * w[j * 12 + t];
    s = s * inv + b[t];
    out[idx] = 1.f / (1.f + expf(-s));
}

// ---------- launch ----------
extern "C" void kernel_launch(void* const* d_in, const int* in_sizes, int n_in,
                              void* d_out, int out_size, void* d_ws, size_t ws_size,
                              hipStream_t stream) {
    const float* x   = (const float*)d_in[0];
    const int*   ei  = (const int*)d_in[1];
    const float* ea  = (const float*)d_in[2];
    const int*   bat = (const int*)d_in[3];
    const float* eew = (const float*)d_in[4];
    const float* eeb = (const float*)d_in[5];
    const float* nw  = (const float*)d_in[6];
    const float* nb  = (const float*)d_in[7];
    const float* fcw = (const float*)d_in[32];
    const float* fcb = (const float*)d_in[33];
    float* out = (float*)d_out;

    char* ws = (char*)d_ws;
    unsigned short* ewT = (unsigned short*)(ws + 0);          // 128*E*2 = 16.78 MB
    unsigned short* w2p = (unsigned short*)(ws + 16777216);   // 132*8KB = 1.06 MB (pad 2MB)
    float* hA    = (float*)(ws + 18874368);                   // N*64*4
    float* hB    = (float*)(ws + 23068672);
    float* htmp  = (float*)(ws + 27262976);
    float* aggr  = (float*)(ws + 31457280);                   // N*64*4, ends 35651584
    float* sums  = (float*)(ws + 35651584);                   // 256 f (contiguous w/ aggr)
    unsigned short* hbf = (unsigned short*)(ws + 35652608);   // N*64*2
    float* deg   = (float*)(ws + 37749760);                   // N*4
    float* scale = (float*)(ws + 37815296);
    float* shift = (float*)(ws + 37815552);
    float* pool  = (float*)(ws + 37815808);                   // G*32*4
    float* cnt   = (float*)(ws + 37881344);                   // G*4

    (void)hipMemsetAsync(deg, 0, NN * 4, stream);
    (void)hipMemsetAsync(pool, 0, NG * 32 * 4 + NG * 4, stream);

    k_nh<<<NN * 64 / 256, 256, 0, stream>>>(x, nw, nb, hA, hbf);
    k_deg<<<NE / 256, 256, 0, stream>>>(ei, deg);

    float* hin = hA;
    float* hout = hB;
    for (int L = 0; L < 3; L++) {
        const float* w1 = (const float*)d_in[8 + 8 * L + 0];
        const float* b1 = (const float*)d_in[8 + 8 * L + 1];
        const float* w2 = (const float*)d_in[8 + 8 * L + 2];
        const float* b2 = (const float*)d_in[8 + 8 * L + 3];
        const float* rt = (const float*)d_in[8 + 8 * L + 4];
        const float* cb = (const float*)d_in[8 + 8 * L + 5];
        const float* bg = (const float*)d_in[8 + 8 * L + 6];
        const float* bb = (const float*)d_in[8 + 8 * L + 7];

        (void)hipMemsetAsync(aggr, 0, NN * 64 * 4 + 1024, stream);  // aggr + sums

        k_ewt<<<NE / 64, 256, 0, stream>>>(ea, eew, eeb, w1, b1, ewT);

        if (L < 2) {
            k_packw2<64><<<132 * 4096 / 256, 256, 0, stream>>>(w2, b2, w2p);
            k_msg_mfma<64><<<NE / 128, 256, 0, stream>>>(ei, hbf, ewT, w2p, aggr);
            k_combine<64><<<NN * 64 / 256, 256, 0, stream>>>(hin, rt, aggr, deg, cb, htmp);
            k_bnstats<64><<<64 * 8, 256, 0, stream>>>(htmp, sums);
            k_bnfinal<64><<<1, 64, 0, stream>>>(sums, bg, bb, scale, shift);
            k_bnapply<64, true><<<NN * 64 / 256, 256, 0, stream>>>(htmp, scale, shift, hout, hbf);
        } else {
            k_packw2<32><<<132 * 2048 / 256, 256, 0, stream>>>(w2, b2, w2p);
            k_msg_mfma<32><<<NE / 128, 256, 0, stream>>>(ei, hbf, ewT, w2p, aggr);
            k_combine<32><<<NN * 32 / 256, 256, 0, stream>>>(hin, rt, aggr, deg, cb, htmp);
            k_bnstats<32><<<32 * 8, 256, 0, stream>>>(htmp, sums);
            k_bnfinal<32><<<1, 64, 0, stream>>>(sums, bg, bb, scale, shift);
            k_bnapply<32, false><<<NN * 32 / 256, 256, 0, stream>>>(htmp, scale, shift, hout, hbf);
        }
        float* tmp = hin; hin = hout; hout = tmp;
    }
    k_pool<<<NN * 32 / 256, 256, 0, stream>>>(hin, bat, pool, cnt);
    k_fc<<<NG * 12 / 256, 256, 0, stream>>>(pool, cnt, fcw, fcb, out);
}